// Round 10
// baseline (141.998 us; speedup 1.0000x reference)
//
#include <hip/hip_runtime.h>
#include <hip/hip_bf16.h>

typedef unsigned int u32;
typedef unsigned long long u64;

#define HH 384
#define WW 768
#define HW (HH*WW)
#define H4 96
#define W4 192
#define DLR 32
#define TOPK 8000
#define NTH 256
#define NBLK (HW/NTH)    // 1152

// k_prob tiling: 4 rows x 64 cols per block
#define PTW 18
#define PTH 3

// jac tiling: interior 48x32, region 64x48, 192 blocks, 3 float4-units/thread
#define JBX 16
#define JBY 12
#define JGRID (JBX*JBY)
#define JRW2 64
#define JRH2 48
#define JIW 48
#define JIH 32
#define JNPT 3

struct SelState { u32 K, all_pass, prefix, r, cutoff, n_take, need_rank; };

// ---- compile-time D-interp tables (bit-identical weights to runtime formula) ----
struct DTab {
    float A[32]; float B[32];
    int f[32]; int l[32];
    float w[128];
};
constexpr DTab mk_dtab(){
    DTab t{};
    const float CD = (float)(31.0/127.0);
    for (int k = 0; k < 32; ++k){ t.A[k]=0.f; t.B[k]=0.f; t.f[k]=-1; t.l[k]=-1; }
    for (int d = 0; d < 128; ++d){
        float pos = (float)d * CD;
        int lo = (int)pos; if (lo > 31) lo = 31;
        int hi = (lo+1 > 31) ? 31 : lo+1;
        float w = pos - (float)lo;
        t.w[d] = w;
        t.A[lo] += 1.0f - w;            t.A[hi] += w;
        t.B[lo] += (float)d*(1.0f - w); t.B[hi] += (float)d*w;
        if (t.f[lo] < 0) t.f[lo] = d;
        t.l[lo] = d;
    }
    return t;
}
static constexpr DTab DT = mk_dtab();

// =============== k_prob: interp + prob stats + confidence ===============
__global__ __launch_bounds__(NTH) void k_prob(const float* __restrict__ P,
        const float* __restrict__ edge, const float* __restrict__ occ,
        float* __restrict__ conf, float* __restrict__ disp0, u32* __restrict__ dhk,
        u32* __restrict__ hist, SelState* st){
    int gtid = blockIdx.x*NTH + threadIdx.x;
    if (gtid < 2*65536) hist[gtid] = 0u;
    if (gtid == 0){
        st->K=0; st->all_pass=0; st->prefix=0; st->r=TOPK; st->cutoff=0; st->n_take=0; st->need_rank=0;
    }

    __shared__ float Sl[DLR][PTH][PTW];
    __shared__ float YL[4][DLR][19];

    int bx = blockIdx.x % 12, by = blockIdx.x / 12;
    int X = bx*64, Y = by*4;
    const float CY = (float)(95.0/383.0);
    const float CX = (float)(191.0/767.0);

    float fy0 = (float)Y * CY; int y0min = (int)fy0; if (y0min > H4-1) y0min = H4-1;
    float fx0 = (float)X * CX; int x0min = (int)fx0; if (x0min > W4-1) x0min = W4-1;

    for (int e = threadIdx.x; e < DLR*PTH*PTW; e += NTH){
        int dl  = e / (PTH*PTW);
        int rem = e % (PTH*PTW);
        int ry  = rem / PTW;
        int cx  = rem % PTW;
        int gy = min(y0min + ry, H4-1);
        int gx = min(x0min + cx, W4-1);
        ((float*)Sl)[e] = P[dl*(H4*W4) + gy*W4 + gx];
    }
    __syncthreads();

    for (int e = threadIdx.x; e < 4*DLR*18; e += NTH){
        int ly  = e / (DLR*18);
        int rem = e % (DLR*18);
        int dl  = rem / 18;
        int cx  = rem % 18;
        float fy = (float)(Y + ly) * CY;
        int y0 = (int)fy; if (y0 > H4-1) y0 = H4-1;
        int y1 = min(y0+1, H4-1);
        float wy = fy - (float)y0;
        int ry = y0 - y0min, ryb = y1 - y0min;
        YL[ly][dl][cx] = Sl[dl][ry][cx]*(1.0f-wy) + Sl[dl][ryb][cx]*wy;
    }
    __syncthreads();

    int lx = threadIdx.x & 63, ly = threadIdx.x >> 6;
    int x = X + lx, y = Y + ly;
    int idx = y*WW + x;

    float fx = (float)x * CX;
    int x0 = (int)fx; if (x0 > W4-1) x0 = W4-1;
    float wx = fx - (float)x0;
    float omwx = 1.0f - wx;
    int cxl = x0 - x0min;

    float S[DLR];
    #pragma unroll
    for (int k = 0; k < DLR; ++k)
        S[k] = YL[ly][k][cxl]*omwx + YL[ly][k][cxl+1]*wx;

    float s0=0.f,s1=0.f,s2=0.f,s3=0.f, u0=0.f,u1=0.f,u2=0.f,u3=0.f;
    #pragma unroll
    for (int k = 0; k < DLR; k += 4){
        s0 = fmaf(DT.A[k  ], S[k  ], s0); u0 = fmaf(DT.B[k  ], S[k  ], u0);
        s1 = fmaf(DT.A[k+1], S[k+1], s1); u1 = fmaf(DT.B[k+1], S[k+1], u1);
        s2 = fmaf(DT.A[k+2], S[k+2], s2); u2 = fmaf(DT.B[k+2], S[k+2], u2);
        s3 = fmaf(DT.A[k+3], S[k+3], s3); u3 = fmaf(DT.B[k+3], S[k+3], u3);
    }
    float sum  = (s0+s1) + (s2+s3);
    float sumd = (u0+u1) + (u2+u3);

    float vmax = -1.f, v2 = -1.f; int dmax = 0;
    #pragma unroll
    for (int k = 0; k < 32; ++k){
        if (DT.f[k] < 0) continue;
        const int d0 = DT.f[k], d1 = DT.l[k];
        const int kh = (k+1 > 31) ? 31 : k+1;
        float Sk = S[k], Sh = S[kh];
        const float w0 = DT.w[d0], w1 = DT.w[d1];
        float vf = Sk*(1.0f-w0) + Sh*w0;
        float vl = Sk*(1.0f-w1) + Sh*w1;
        bool up = vl > vf;
        float segv = up ? vl : vf;
        int   segd = up ? d1 : d0;
        float vr = -1.f;
        if (d1 > d0){
            const float wa = DT.w[d1-1], wb = DT.w[d0+1];
            float va = Sk*(1.0f-wa) + Sh*wa;
            float vb = Sk*(1.0f-wb) + Sh*wb;
            vr = up ? va : vb;
        }
        if (segv > vmax){ v2 = fmaxf(vmax, vr); vmax = segv; dmax = segd; }
        else            { v2 = fmaxf(v2, segv); }
    }

    float inv  = 1.0f/(sum + 1e-6f);
    float pmax = vmax*inv, p2 = v2*inv;
    float psr  = pmax/(p2 + 1e-6f);
    float cf   = pmax * tanhf(psr);
    cf *= expf(-2.0f*edge[idx]) * fmaxf(1.0f - occ[idx], 0.0f);
    conf[idx]  = cf;
    disp0[idx] = sumd*inv;
    dhk[idx]   = (u32)dmax;
}

// =============== k_nms: LDS-staged 3x3 NMS + edge weights + K + hi16 hist ===============
__global__ __launch_bounds__(NTH) void k_nms(const float* __restrict__ conf,
        const float* __restrict__ edge, const float* __restrict__ occ,
        u32* __restrict__ dhk, float4* __restrict__ w4raw,
        u32* __restrict__ hist_hi, SelState* st){
    __shared__ float Cs[6][66];
    __shared__ float Es[6][66];
    __shared__ float Os[6][66];
    int bx = blockIdx.x % 12, by = blockIdx.x / 12;
    int X = bx*64, Y = by*4;
    for (int e = threadIdx.x; e < 6*66; e += NTH){
        int ry = e / 66, cx = e % 66;
        int gy = Y + ry - 1, gx = X + cx - 1;
        bool in = ((u32)gy < (u32)HH) && ((u32)gx < (u32)WW);
        int cg = min(max(gy,0),HH-1)*WW + min(max(gx,0),WW-1);
        Cs[ry][cx] = in ? conf[cg] : -INFINITY;
        Es[ry][cx] = edge[cg];
        Os[ry][cx] = occ[cg];
    }
    __syncthreads();

    int lx = threadIdx.x & 63, ly = threadIdx.x >> 6;
    int x = X + lx, y = Y + ly;
    int idx = y*WW + x;

    float c = Cs[ly+1][lx+1];
    float pool = Cs[ly][lx];
    pool = fmaxf(pool, Cs[ly  ][lx+1]); pool = fmaxf(pool, Cs[ly  ][lx+2]);
    pool = fmaxf(pool, Cs[ly+1][lx  ]); pool = fmaxf(pool, Cs[ly+1][lx+1]);
    pool = fmaxf(pool, Cs[ly+1][lx+2]);
    pool = fmaxf(pool, Cs[ly+2][lx  ]); pool = fmaxf(pool, Cs[ly+2][lx+1]);
    pool = fmaxf(pool, Cs[ly+2][lx+2]);
    bool keep = (c >= 0.1f) && (c >= pool);
    dhk[idx] |= keep ? 256u : 0u;

    float e  = Es[ly+1][lx+1], o  = Os[ly+1][lx+1];
    float e1 = Es[ly+2][lx+1], o1 = Os[ly+2][lx+1];   // up-shift = row y+1
    float e2 = Es[ly  ][lx+1], o2 = Os[ly  ][lx+1];   // down-shift = row y-1
    float e3 = Es[ly+1][lx+2], o3 = Os[ly+1][lx+2];   // left-shift = col x+1
    float e4 = Es[ly+1][lx  ], o4 = Os[ly+1][lx  ];   // right-shift = col x-1
    float4 wp;
    wp.x = expf(-(e+e1))*(1.f-o)*(1.f-o1);
    wp.y = expf(-(e+e2))*(1.f-o)*(1.f-o2);
    wp.z = expf(-(e+e3))*(1.f-o)*(1.f-o3);
    wp.w = expf(-(e+e4))*(1.f-o)*(1.f-o4);
    w4raw[idx] = wp;

    if (keep) atomicAdd(&hist_hi[__float_as_uint(c) >> 16], 1u);

    u64 m = __ballot(keep);
    __shared__ u32 wc[4];
    int lane = threadIdx.x & 63, wid = threadIdx.x >> 6;
    if (lane == 0) wc[wid] = (u32)__popcll(m);
    __syncthreads();
    if (threadIdx.x == 0) atomicAdd(&st->K, wc[0]+wc[1]+wc[2]+wc[3]);
}

// ---- hi16 select (1 block, 1024 threads, uint4 loads) ----
__global__ __launch_bounds__(1024) void k_advhi(const u32* __restrict__ hist, SelState* st){
    __shared__ u32 ps[1024];
    __shared__ u32 csum[256];
    int t = threadIdx.x;
    const uint4* h4 = (const uint4*)hist;
    u32 s = 0;
    #pragma unroll
    for (int i = 0; i < 16; ++i){ uint4 v = h4[t*16 + i]; s += v.x+v.y+v.z+v.w; }
    ps[t] = s;
    __syncthreads();
    if (t < 256) csum[t] = ps[4*t] + ps[4*t+1] + ps[4*t+2] + ps[4*t+3];
    __syncthreads();
    if (t == 0){
        if (st->K <= TOPK){ st->all_pass = 1; }
        else {
            u32 r = TOPK, suf = 0; int tb = 0;
            for (int u = 255; u >= 0; --u){
                if (r <= suf + csum[u]){ tb = u; break; }
                suf += csum[u];
            }
            u32 c = suf;
            for (int i = 255; i >= 0; --i){
                u32 h = hist[tb*256 + i];
                if (r <= c + h){ st->prefix = (u32)(tb*256 + i); st->r = r - c; break; }
                c += h;
            }
        }
    }
}

// ---- lo16 histogram ----
__global__ __launch_bounds__(NTH) void k_histlo(const float* __restrict__ conf,
        const u32* __restrict__ dhk, const SelState* st, u32* __restrict__ hist_lo){
    if (st->all_pass) return;
    int idx = blockIdx.x*NTH + threadIdx.x;
    u32 dv = dhk[idx];
    if (dv & 256u){
        u32 key = __float_as_uint(conf[idx]);
        if ((key >> 16) == st->prefix) atomicAdd(&hist_lo[key & 0xffffu], 1u);
    }
}

// ---- lo16 select (1 block, 1024 threads) ----
__global__ __launch_bounds__(1024) void k_advlo(const u32* __restrict__ hist, SelState* st){
    if (st->all_pass) return;
    __shared__ u32 ps[1024];
    __shared__ u32 csum[256];
    int t = threadIdx.x;
    const uint4* h4 = (const uint4*)hist;
    u32 s = 0;
    #pragma unroll
    for (int i = 0; i < 16; ++i){ uint4 v = h4[t*16 + i]; s += v.x+v.y+v.z+v.w; }
    ps[t] = s;
    __syncthreads();
    if (t < 256) csum[t] = ps[4*t] + ps[4*t+1] + ps[4*t+2] + ps[4*t+3];
    __syncthreads();
    if (t == 0){
        u32 r = st->r, suf = 0; int tb = 0;
        for (int u = 255; u >= 0; --u){
            if (r <= suf + csum[u]){ tb = u; break; }
            suf += csum[u];
        }
        u32 c = suf;
        for (int i = 255; i >= 0; --i){
            u32 h = hist[tb*256 + i];
            if (r <= c + h){
                st->cutoff = (st->prefix << 16) | (u32)(tb*256 + i);
                st->n_take = r - c;
                st->need_rank = ((r - c) != h) ? 1u : 0u;
                break;
            }
            c += h;
        }
    }
}

// ---- per-block count of cutoff-equal anchors (gated) ----
__global__ __launch_bounds__(NTH) void k_eqcnt(const float* __restrict__ conf,
        const u32* __restrict__ dhk, const SelState* st, u32* __restrict__ blk_cnt){
    if (st->all_pass || !st->need_rank) return;
    int idx = blockIdx.x*NTH + threadIdx.x;
    u32 dv = dhk[idx];
    bool flag = (dv & 256u) && (__float_as_uint(conf[idx]) == st->cutoff);
    u64 m = __ballot(flag);
    __shared__ u32 wc[4];
    if ((threadIdx.x & 63) == 0) wc[threadIdx.x >> 6] = (u32)__popcll(m);
    __syncthreads();
    if (threadIdx.x == 0) blk_cnt[blockIdx.x] = wc[0]+wc[1]+wc[2]+wc[3];
}

// ---- exclusive scan of block counts (1 block, gated) ----
__global__ void k_scan(const u32* __restrict__ blk_cnt, u32* __restrict__ blk_off,
                       const SelState* st){
    if (st->all_pass || !st->need_rank) return;
    __shared__ u32 s[256];
    int t = threadIdx.x;
    u32 v[5]; u32 loc = 0;
    #pragma unroll
    for (int i = 0; i < 5; ++i){
        int j = t*5 + i;
        u32 c = (j < NBLK) ? blk_cnt[j] : 0;
        v[i] = loc; loc += c;
    }
    s[t] = loc;
    __syncthreads();
    for (int off = 1; off < 256; off <<= 1){
        u32 x = (t >= off) ? s[t-off] : 0;
        __syncthreads();
        s[t] += x;
        __syncthreads();
    }
    u32 base = (t > 0) ? s[t-1] : 0;
    #pragma unroll
    for (int i = 0; i < 5; ++i){
        int j = t*5 + i;
        if (j < NBLK) blk_off[j] = base + v[i];
    }
}

// ---- mark: clear keep-bit for cutoff-tied anchors beyond n_take (gated) ----
__global__ __launch_bounds__(NTH) void k_mark(const float* __restrict__ conf,
        u32* __restrict__ dhk, const SelState* st, const u32* __restrict__ blk_off){
    if (st->all_pass || !st->need_rank) return;
    int idx = blockIdx.x*NTH + threadIdx.x;
    u32 dv = dhk[idx];
    bool eq = (dv & 256u) && (__float_as_uint(conf[idx]) == st->cutoff);
    u64 m = __ballot(eq);
    __shared__ u32 wc[4];
    int lane = threadIdx.x & 63, wid = threadIdx.x >> 6;
    if (lane == 0) wc[wid] = (u32)__popcll(m);
    __syncthreads();
    u32 before = (u32)__popcll(m & ((1ull << lane) - 1ull));
    for (int w = 0; w < wid; ++w) before += wc[w];
    if (eq && (blk_off[blockIdx.x] + before >= st->n_take))
        dhk[idx] = dv & ~256u;
}

// =============== jac: K sweeps; W/N/center in regs, R in LDS float4 units ===============
template<int FUSED, int FINAL>
__global__ __launch_bounds__(NTH) void k_jacT(
        const float* __restrict__ Rin, float* __restrict__ Rout,
        const float4* __restrict__ Wp, const float* __restrict__ Nh,
        float4* __restrict__ Ws, float* __restrict__ Nho,
        const float* __restrict__ conf, const float* __restrict__ disp0,
        const u32* __restrict__ dhk, const SelState* __restrict__ st,
        float* __restrict__ out, int K){
    __shared__ float Rs[2][JRH2*JRW2];    // 2 x 12 KB
    int tid = threadIdx.x;
    int bx = blockIdx.x & 15, by = blockIdx.x >> 4;
    int ry0 = by*JIH - 8, cx0 = bx*JIW - 8;

    float4 Wt[JNPT][4];
    float4 Nt[JNPT];
    float4 Ct[JNPT];

    u32 ap = 0, cut = 0;
    if (FUSED){ ap = st->all_pass; cut = st->cutoff; }

    #pragma unroll
    for (int k = 0; k < JNPT; ++k){
        int u = tid + k*NTH;
        int r = u >> 4, c = (u & 15) << 2;
        int gy = ry0 + r;
        int cgy = min(max(gy,0),HH-1);
        float4 n4, r4;
        #pragma unroll
        for (int j = 0; j < 4; ++j){
            int gx = cx0 + c + j;
            int cgx = min(max(gx,0),WW-1);
            int g = cgy*WW + cgx;
            if (FUSED){
                u32 dv = dhk[g];
                float cf = conf[g];
                bool kf = (dv & 256u) && (ap || (__float_as_uint(cf) >= cut));
                float mm = kf ? fminf(fmaxf(cf, 0.0f), 1.0f) : 0.0f;
                float4 wr = Wp[g];
                float wsum = wr.x + wr.y + wr.z + wr.w + 1e-6f;
                float den = mm + 0.8f*wsum + 1e-6f;
                float n0 = mm * ((float)(dv & 255u) - disp0[g]);
                float nh = n0 / den;
                float sc = 0.8f / den;
                wr.x *= sc; wr.y *= sc; wr.z *= sc; wr.w *= sc;
                Wt[k][j] = wr;
                ((float*)&n4)[j] = nh;
                ((float*)&r4)[j] = nh;
            } else {
                Wt[k][j] = Wp[g];
                ((float*)&n4)[j] = Nh[g];
                ((float*)&r4)[j] = Rin[g];
            }
        }
        Nt[k] = n4; Ct[k] = r4;
        *(float4*)&Rs[0][r*JRW2 + c] = r4;
        if (FUSED){
            if (r >= 8 && r < 8+JIH && c >= 8 && c < 8+JIW){
                int g2 = (ry0 + r)*WW + (cx0 + c);
                #pragma unroll
                for (int j = 0; j < 4; ++j) Ws[g2 + j] = Wt[k][j];
                *(float4*)&Nho[g2] = n4;
            }
        }
    }
    __syncthreads();

    int cur = 0;
    for (int ts = 1; ts <= K; ++ts){
        #pragma unroll
        for (int k = 0; k < JNPT; ++k){
            int u = tid + k*NTH;
            int r = u >> 4, c = (u & 15) << 2;
            int gy = ry0 + r;
            float4 C = Ct[k];
            int rm = (r > 0) ? r-1 : r;
            int rp = (r < JRH2-1) ? r+1 : r;
            float4 up = *(const float4*)&Rs[cur][rm*JRW2 + c];
            float4 dn = *(const float4*)&Rs[cur][rp*JRW2 + c];
            if (gy == 0)    up = C;
            if (gy == HH-1) dn = C;
            float xl = Rs[cur][r*JRW2 + ((c > 0) ? c-1 : c)];
            float xr = Rs[cur][r*JRW2 + ((c+4 < JRW2) ? c+4 : JRW2-1)];
            int gx0 = cx0 + c;
            if (gx0 == 0)        xl = C.x;
            if (gx0 + 3 == WW-1) xr = C.w;
            float4 nv;
            nv.x = Nt[k].x + Wt[k][0].x*up.x + Wt[k][0].y*dn.x + Wt[k][0].z*xl  + Wt[k][0].w*C.y;
            nv.y = Nt[k].y + Wt[k][1].x*up.y + Wt[k][1].y*dn.y + Wt[k][1].z*C.x + Wt[k][1].w*C.z;
            nv.z = Nt[k].z + Wt[k][2].x*up.z + Wt[k][2].y*dn.z + Wt[k][2].z*C.y + Wt[k][2].w*C.w;
            nv.w = Nt[k].w + Wt[k][3].x*up.w + Wt[k][3].y*dn.w + Wt[k][3].z*C.z + Wt[k][3].w*xr;
            bool rowin = (r >= ts) && (r < JRH2 - ts);
            int cl = ts, ch = JRW2 - ts;
            nv.x = (rowin && c   >= cl && c   < ch) ? nv.x : C.x;
            nv.y = (rowin && c+1 >= cl && c+1 < ch) ? nv.y : C.y;
            nv.z = (rowin && c+2 >= cl && c+2 < ch) ? nv.z : C.z;
            nv.w = (rowin && c+3 >= cl && c+3 < ch) ? nv.w : C.w;
            *(float4*)&Rs[cur^1][r*JRW2 + c] = nv;
            Ct[k] = nv;
        }
        __syncthreads();
        cur ^= 1;
    }

    #pragma unroll
    for (int k = 0; k < JNPT; ++k){
        int u = tid + k*NTH;
        int r = u >> 4, c = (u & 15) << 2;
        if (r >= 8 && r < 8+JIH && c >= 8 && c < 8+JIW){
            int g = (ry0 + r)*WW + (cx0 + c);
            if (FINAL){
                float4 d0 = *(const float4*)&disp0[g];
                float4 o;
                o.x = fmaxf(d0.x + Ct[k].x, 0.0f);
                o.y = fmaxf(d0.y + Ct[k].y, 0.0f);
                o.z = fmaxf(d0.z + Ct[k].z, 0.0f);
                o.w = fmaxf(d0.w + Ct[k].w, 0.0f);
                *(float4*)&out[g] = o;
            } else {
                *(float4*)&Rout[g] = Ct[k];
            }
        }
    }
}

extern "C" void kernel_launch(void* const* d_in, const int* in_sizes, int n_in,
                              void* d_out, int out_size, void* d_ws, size_t ws_size,
                              hipStream_t stream) {
    const float* P    = (const float*)d_in[0];
    const float* edge = (const float*)d_in[1];
    const float* occ  = (const float*)d_in[2];
    float* out = (float*)d_out;

    float*  conf   = (float*)d_ws;
    float*  disp0  = conf + HW;
    float*  nhat   = disp0 + HW;
    float*  Ra     = nhat + HW;
    float*  Rb     = Ra + HW;
    u32*    dhk    = (u32*)(Rb + HW);
    float4* w4raw  = (float4*)(dhk + HW);     // offset 6*HW*4 B, 16B aligned
    float4* w4s    = w4raw + HW;
    u32*    hist   = (u32*)(w4s + HW);
    u32*    hist_hi = hist;
    u32*    hist_lo = hist + 65536;
    u32*    blk_cnt = hist_lo + 65536;
    u32*    blk_off = blk_cnt + NBLK;
    SelState* st   = (SelState*)(blk_off + NBLK);

    dim3 grid(NBLK), block(NTH);
    k_prob<<<grid, block, 0, stream>>>(P, edge, occ, conf, disp0, dhk, hist, st);
    k_nms<<<grid, block, 0, stream>>>(conf, edge, occ, dhk, w4raw, hist_hi, st);
    k_advhi<<<1, 1024, 0, stream>>>(hist_hi, st);
    k_histlo<<<grid, block, 0, stream>>>(conf, dhk, st, hist_lo);
    k_advlo<<<1, 1024, 0, stream>>>(hist_lo, st);
    k_eqcnt<<<grid, block, 0, stream>>>(conf, dhk, st, blk_cnt);
    k_scan<<<1, 256, 0, stream>>>(blk_cnt, blk_off, st);
    k_mark<<<grid, block, 0, stream>>>(conf, dhk, st, blk_off);

    dim3 jgrid(JGRID);
    // launch 1 (fused finalmaps): iter 1 in staging + sweeps 2..9
    k_jacT<1,0><<<jgrid, block, 0, stream>>>(nullptr, Ra, w4raw, nullptr, w4s, nhat,
                                             conf, disp0, dhk, st, out, 8);
    // sweeps 10..17
    k_jacT<0,0><<<jgrid, block, 0, stream>>>(Ra, Rb, w4s, nhat, nullptr, nullptr,
                                             conf, disp0, dhk, st, out, 8);
    // sweeps 18..25
    k_jacT<0,0><<<jgrid, block, 0, stream>>>(Rb, Ra, w4s, nhat, nullptr, nullptr,
                                             conf, disp0, dhk, st, out, 8);
    // sweeps 26..30 + clip
    k_jacT<0,1><<<jgrid, block, 0, stream>>>(Ra, nullptr, w4s, nhat, nullptr, nullptr,
                                             conf, disp0, dhk, st, out, 5);
}

// Round 11
// 133.684 us; speedup vs baseline: 1.0622x; 1.0622x over previous
//
#include <hip/hip_runtime.h>
#include <hip/hip_bf16.h>

typedef unsigned int u32;
typedef unsigned long long u64;

#define HH 384
#define WW 768
#define HW (HH*WW)
#define H4 96
#define W4 192
#define DLR 32
#define TOPK 8000
#define NTH 256
#define NBLK (HW/NTH)    // 1152

// k_prob tiling: 4 rows x 64 cols per block
#define PTW 18
#define PTH 3

// jac tiling: interior 48x32, halo 12 -> region 72x56, 192 blocks
#define JIW 48
#define JIH 32
#define JH  12
#define JRW 72
#define JRH 56
#define JNU (JRH*(JRW/4))   // 56*18 = 1008
#define JGRID 192

struct SelState { u32 K, cutoff, idxcut; };

// ---- compile-time D-interp tables (bit-identical weights to runtime formula) ----
struct DTab {
    float A[32]; float B[32];
    int f[32]; int l[32];
    float w[128];
};
constexpr DTab mk_dtab(){
    DTab t{};
    const float CD = (float)(31.0/127.0);
    for (int k = 0; k < 32; ++k){ t.A[k]=0.f; t.B[k]=0.f; t.f[k]=-1; t.l[k]=-1; }
    for (int d = 0; d < 128; ++d){
        float pos = (float)d * CD;
        int lo = (int)pos; if (lo > 31) lo = 31;
        int hi = (lo+1 > 31) ? 31 : lo+1;
        float w = pos - (float)lo;
        t.w[d] = w;
        t.A[lo] += 1.0f - w;            t.A[hi] += w;
        t.B[lo] += (float)d*(1.0f - w); t.B[hi] += (float)d*w;
        if (t.f[lo] < 0) t.f[lo] = d;
        t.l[lo] = d;
    }
    return t;
}
static constexpr DTab DT = mk_dtab();

// =============== k_prob: interp + prob stats + confidence ===============
__global__ __launch_bounds__(NTH) void k_prob(const float* __restrict__ P,
        const float* __restrict__ edge, const float* __restrict__ occ,
        float* __restrict__ conf, float* __restrict__ disp0, u32* __restrict__ dhk,
        SelState* st){
    if (blockIdx.x == 0 && threadIdx.x == 0){
        st->K = 0; st->cutoff = 0; st->idxcut = 0x7FFFFFFFu;
    }

    __shared__ float Sl[DLR][PTH][PTW];
    __shared__ float YL[4][DLR][19];

    int bx = blockIdx.x % 12, by = blockIdx.x / 12;
    int X = bx*64, Y = by*4;
    const float CY = (float)(95.0/383.0);
    const float CX = (float)(191.0/767.0);

    float fy0 = (float)Y * CY; int y0min = (int)fy0; if (y0min > H4-1) y0min = H4-1;
    float fx0 = (float)X * CX; int x0min = (int)fx0; if (x0min > W4-1) x0min = W4-1;

    for (int e = threadIdx.x; e < DLR*PTH*PTW; e += NTH){
        int dl  = e / (PTH*PTW);
        int rem = e % (PTH*PTW);
        int ry  = rem / PTW;
        int cx  = rem % PTW;
        int gy = min(y0min + ry, H4-1);
        int gx = min(x0min + cx, W4-1);
        ((float*)Sl)[e] = P[dl*(H4*W4) + gy*W4 + gx];
    }
    __syncthreads();

    for (int e = threadIdx.x; e < 4*DLR*18; e += NTH){
        int ly  = e / (DLR*18);
        int rem = e % (DLR*18);
        int dl  = rem / 18;
        int cx  = rem % 18;
        float fy = (float)(Y + ly) * CY;
        int y0 = (int)fy; if (y0 > H4-1) y0 = H4-1;
        int y1 = min(y0+1, H4-1);
        float wy = fy - (float)y0;
        int ry = y0 - y0min, ryb = y1 - y0min;
        YL[ly][dl][cx] = Sl[dl][ry][cx]*(1.0f-wy) + Sl[dl][ryb][cx]*wy;
    }
    __syncthreads();

    int lx = threadIdx.x & 63, ly = threadIdx.x >> 6;
    int x = X + lx, y = Y + ly;
    int idx = y*WW + x;

    float fx = (float)x * CX;
    int x0 = (int)fx; if (x0 > W4-1) x0 = W4-1;
    float wx = fx - (float)x0;
    float omwx = 1.0f - wx;
    int cxl = x0 - x0min;

    float S[DLR];
    #pragma unroll
    for (int k = 0; k < DLR; ++k)
        S[k] = YL[ly][k][cxl]*omwx + YL[ly][k][cxl+1]*wx;

    float s0=0.f,s1=0.f,s2=0.f,s3=0.f, u0=0.f,u1=0.f,u2=0.f,u3=0.f;
    #pragma unroll
    for (int k = 0; k < DLR; k += 4){
        s0 = fmaf(DT.A[k  ], S[k  ], s0); u0 = fmaf(DT.B[k  ], S[k  ], u0);
        s1 = fmaf(DT.A[k+1], S[k+1], s1); u1 = fmaf(DT.B[k+1], S[k+1], u1);
        s2 = fmaf(DT.A[k+2], S[k+2], s2); u2 = fmaf(DT.B[k+2], S[k+2], u2);
        s3 = fmaf(DT.A[k+3], S[k+3], s3); u3 = fmaf(DT.B[k+3], S[k+3], u3);
    }
    float sum  = (s0+s1) + (s2+s3);
    float sumd = (u0+u1) + (u2+u3);

    float vmax = -1.f, v2 = -1.f; int dmax = 0;
    #pragma unroll
    for (int k = 0; k < 32; ++k){
        if (DT.f[k] < 0) continue;
        const int d0 = DT.f[k], d1 = DT.l[k];
        const int kh = (k+1 > 31) ? 31 : k+1;
        float Sk = S[k], Sh = S[kh];
        const float w0 = DT.w[d0], w1 = DT.w[d1];
        float vf = Sk*(1.0f-w0) + Sh*w0;
        float vl = Sk*(1.0f-w1) + Sh*w1;
        bool up = vl > vf;
        float segv = up ? vl : vf;
        int   segd = up ? d1 : d0;
        float vr = -1.f;
        if (d1 > d0){
            const float wa = DT.w[d1-1], wb = DT.w[d0+1];
            float va = Sk*(1.0f-wa) + Sh*wa;
            float vb = Sk*(1.0f-wb) + Sh*wb;
            vr = up ? va : vb;
        }
        if (segv > vmax){ v2 = fmaxf(vmax, vr); vmax = segv; dmax = segd; }
        else            { v2 = fmaxf(v2, segv); }
    }

    float inv  = 1.0f/(sum + 1e-6f);
    float pmax = vmax*inv, p2 = v2*inv;
    float psr  = pmax/(p2 + 1e-6f);
    float cf   = pmax * tanhf(psr);
    cf *= expf(-2.0f*edge[idx]) * fmaxf(1.0f - occ[idx], 0.0f);
    conf[idx]  = cf;
    disp0[idx] = sumd*inv;
    dhk[idx]   = (u32)dmax;
}

// =============== k_nms: staged NMS + edge weights + compact anchor list ===============
__global__ __launch_bounds__(NTH) void k_nms(const float* __restrict__ conf,
        const float* __restrict__ edge, const float* __restrict__ occ,
        u32* __restrict__ dhk, float4* __restrict__ w4raw,
        u64* __restrict__ list, SelState* st){
    __shared__ float Cs[6][66];
    __shared__ float Es[6][66];
    __shared__ float Os[6][66];
    int bx = blockIdx.x % 12, by = blockIdx.x / 12;
    int X = bx*64, Y = by*4;
    for (int e = threadIdx.x; e < 6*66; e += NTH){
        int ry = e / 66, cx = e % 66;
        int gy = Y + ry - 1, gx = X + cx - 1;
        bool in = ((u32)gy < (u32)HH) && ((u32)gx < (u32)WW);
        int cg = min(max(gy,0),HH-1)*WW + min(max(gx,0),WW-1);
        Cs[ry][cx] = in ? conf[cg] : -INFINITY;
        Es[ry][cx] = edge[cg];
        Os[ry][cx] = occ[cg];
    }
    __syncthreads();

    int lx = threadIdx.x & 63, ly = threadIdx.x >> 6;
    int x = X + lx, y = Y + ly;
    int idx = y*WW + x;

    float c = Cs[ly+1][lx+1];
    float pool = Cs[ly][lx];
    pool = fmaxf(pool, Cs[ly  ][lx+1]); pool = fmaxf(pool, Cs[ly  ][lx+2]);
    pool = fmaxf(pool, Cs[ly+1][lx  ]); pool = fmaxf(pool, Cs[ly+1][lx+1]);
    pool = fmaxf(pool, Cs[ly+1][lx+2]);
    pool = fmaxf(pool, Cs[ly+2][lx  ]); pool = fmaxf(pool, Cs[ly+2][lx+1]);
    pool = fmaxf(pool, Cs[ly+2][lx+2]);
    bool keep = (c >= 0.1f) && (c >= pool);
    dhk[idx] |= keep ? 256u : 0u;

    float e  = Es[ly+1][lx+1], o  = Os[ly+1][lx+1];
    float e1 = Es[ly+2][lx+1], o1 = Os[ly+2][lx+1];
    float e2 = Es[ly  ][lx+1], o2 = Os[ly  ][lx+1];
    float e3 = Es[ly+1][lx+2], o3 = Os[ly+1][lx+2];
    float e4 = Es[ly+1][lx  ], o4 = Os[ly+1][lx  ];
    float4 wp;
    wp.x = expf(-(e+e1))*(1.f-o)*(1.f-o1);
    wp.y = expf(-(e+e2))*(1.f-o)*(1.f-o2);
    wp.z = expf(-(e+e3))*(1.f-o)*(1.f-o3);
    wp.w = expf(-(e+e4))*(1.f-o)*(1.f-o4);
    w4raw[idx] = wp;

    // compact-list append (block-aggregated single atomic)
    u64 m = __ballot(keep);
    int lane = threadIdx.x & 63, wid = threadIdx.x >> 6;
    __shared__ u32 wc[4];
    __shared__ u32 wpre[4];
    __shared__ u32 bb;
    if (lane == 0) wc[wid] = (u32)__popcll(m);
    __syncthreads();
    if (threadIdx.x == 0){
        u32 s = 0;
        #pragma unroll
        for (int w = 0; w < 4; ++w){ wpre[w] = s; s += wc[w]; }
        bb = atomicAdd(&st->K, s);
    }
    __syncthreads();
    if (keep){
        u32 before = (u32)__popcll(m & ((1ull << lane) - 1ull));
        u32 pos = bb + wpre[wid] + before;
        list[pos] = ((u64)__float_as_uint(c) << 32) | (u32)idx;
    }
}

// =============== k_sel: single-block exact top-K cutoff (radix + tie-rank) ===============
__global__ __launch_bounds__(1024) void k_sel(const u64* __restrict__ list, SelState* st){
    u32 n = st->K;
    if (n <= TOPK) return;      // defaults (cutoff=0, idxcut=max) already correct
    __shared__ u32 h[256];
    __shared__ u32 bc[3];
    int t = threadIdx.x;

    u32 prefix = 0, rem = TOPK, tie_h = 0;
    for (int b = 3; b >= 0; --b){
        if (t < 256) h[t] = 0;
        __syncthreads();
        int shift = 8*b;
        for (u32 i = t; i < n; i += 1024){
            u32 key = (u32)(list[i] >> 32);
            if ((((u64)(key ^ prefix)) >> (shift+8)) == 0)
                atomicAdd(&h[(key >> shift) & 255u], 1u);
        }
        __syncthreads();
        if (t == 0){
            u32 cum = 0; int dg = 0; u32 hh = 0;
            for (int d = 255; d >= 0; --d){
                hh = h[d];
                if (rem <= cum + hh){ dg = d; break; }
                cum += hh;
            }
            bc[0] = (u32)dg; bc[1] = rem - cum; bc[2] = hh;
        }
        __syncthreads();
        prefix |= bc[0] << shift; rem = bc[1]; tie_h = bc[2];
        __syncthreads();
    }

    u32 idxcut = 0x7FFFFFFFu;
    if (rem != tie_h){
        // rank ties by ascending pixel index: find rem-th smallest idx among tied
        u32 iprefix = 0, irem = rem;
        for (int b = 2; b >= 0; --b){
            if (t < 256) h[t] = 0;
            __syncthreads();
            int shift = 8*b;
            for (u32 i = t; i < n; i += 1024){
                u64 e = list[i];
                u32 key = (u32)(e >> 32);
                u32 idx = (u32)e;
                if (key == prefix && (((u64)(idx ^ iprefix)) >> (shift+8)) == 0)
                    atomicAdd(&h[(idx >> shift) & 255u], 1u);
            }
            __syncthreads();
            if (t == 0){
                u32 cum = 0; int dg = 0;
                for (int d = 0; d < 256; ++d){
                    u32 hh = h[d];
                    if (irem <= cum + hh){ dg = d; break; }
                    cum += hh;
                }
                bc[0] = (u32)dg; bc[1] = irem - cum;
            }
            __syncthreads();
            iprefix |= bc[0] << shift; irem = bc[1];
            __syncthreads();
        }
        idxcut = iprefix;
    }
    if (t == 0){ st->cutoff = prefix; st->idxcut = idxcut; }
}

// =============== jac: K sweeps; W/N/center in regs, R in LDS float4 units ===============
template<int FUSED, int FINAL>
__global__ __launch_bounds__(NTH) void k_jacT(
        const float* __restrict__ Rin, float* __restrict__ Rout,
        const float4* __restrict__ Wp, const float* __restrict__ Nh,
        float4* __restrict__ Ws, float* __restrict__ Nho,
        const float* __restrict__ conf, const float* __restrict__ disp0,
        const u32* __restrict__ dhk, const SelState* __restrict__ st,
        float* __restrict__ out, int K){
    __shared__ float Rs[2][JRH*JRW];    // 2 x 16128 B
    int tid = threadIdx.x;
    int bx = blockIdx.x & 15, by = blockIdx.x >> 4;
    int ry0 = by*JIH - JH, cx0 = bx*JIW - JH;

    float4 Wt[4][4];
    float4 Nt[4];
    float4 Ct[4];

    u32 cut = 0, idxcut = 0;
    if (FUSED){ cut = st->cutoff; idxcut = st->idxcut; }

    #pragma unroll
    for (int k = 0; k < 4; ++k){
        int u = tid + k*NTH;
        if (u < JNU){
            int r = u / 18, c = (u % 18) << 2;
            int gy = ry0 + r;
            int cgy = min(max(gy,0),HH-1);
            float4 n4, r4;
            #pragma unroll
            for (int j = 0; j < 4; ++j){
                int gx = cx0 + c + j;
                int cgx = min(max(gx,0),WW-1);
                int g = cgy*WW + cgx;
                if (FUSED){
                    u32 dv = dhk[g];
                    float cf = conf[g];
                    u32 key = __float_as_uint(cf);
                    bool kf = (dv & 256u) &&
                              (key > cut || (key == cut && (u32)g <= idxcut));
                    float mm = kf ? fminf(fmaxf(cf, 0.0f), 1.0f) : 0.0f;
                    float4 wr = Wp[g];
                    float wsum = wr.x + wr.y + wr.z + wr.w + 1e-6f;
                    float den = mm + 0.8f*wsum + 1e-6f;
                    float n0 = mm * ((float)(dv & 255u) - disp0[g]);
                    float nh = n0 / den;
                    float sc = 0.8f / den;
                    wr.x *= sc; wr.y *= sc; wr.z *= sc; wr.w *= sc;
                    Wt[k][j] = wr;
                    ((float*)&n4)[j] = nh;
                    ((float*)&r4)[j] = nh;
                } else {
                    Wt[k][j] = Wp[g];
                    ((float*)&n4)[j] = Nh[g];
                    ((float*)&r4)[j] = Rin[g];
                }
            }
            Nt[k] = n4; Ct[k] = r4;
            *(float4*)&Rs[0][r*JRW + c] = r4;
            if (FUSED){
                if (r >= JH && r < JH+JIH && c >= JH && c < JH+JIW){
                    int g2 = (ry0 + r)*WW + (cx0 + c);
                    #pragma unroll
                    for (int j = 0; j < 4; ++j) Ws[g2 + j] = Wt[k][j];
                    *(float4*)&Nho[g2] = n4;
                }
            }
        }
    }
    __syncthreads();

    int cur = 0;
    for (int ts = 1; ts <= K; ++ts){
        #pragma unroll
        for (int k = 0; k < 4; ++k){
            int u = tid + k*NTH;
            if (u < JNU){
                int r = u / 18, c = (u % 18) << 2;
                int gy = ry0 + r;
                float4 C = Ct[k];
                int rm = (r > 0) ? r-1 : r;
                int rp = (r < JRH-1) ? r+1 : r;
                float4 up = *(const float4*)&Rs[cur][rm*JRW + c];
                float4 dn = *(const float4*)&Rs[cur][rp*JRW + c];
                if (gy == 0)    up = C;
                if (gy == HH-1) dn = C;
                float xl = Rs[cur][r*JRW + ((c > 0) ? c-1 : c)];
                float xr = Rs[cur][r*JRW + ((c+4 < JRW) ? c+4 : JRW-1)];
                int gx0 = cx0 + c;
                if (gx0 == 0)        xl = C.x;
                if (gx0 + 3 == WW-1) xr = C.w;
                float4 nv;
                nv.x = Nt[k].x + Wt[k][0].x*up.x + Wt[k][0].y*dn.x + Wt[k][0].z*xl  + Wt[k][0].w*C.y;
                nv.y = Nt[k].y + Wt[k][1].x*up.y + Wt[k][1].y*dn.y + Wt[k][1].z*C.x + Wt[k][1].w*C.z;
                nv.z = Nt[k].z + Wt[k][2].x*up.z + Wt[k][2].y*dn.z + Wt[k][2].z*C.y + Wt[k][2].w*C.w;
                nv.w = Nt[k].w + Wt[k][3].x*up.w + Wt[k][3].y*dn.w + Wt[k][3].z*C.z + Wt[k][3].w*xr;
                bool rowin = (r >= ts) && (r < JRH - ts);
                int cl = ts, ch = JRW - ts;
                nv.x = (rowin && c   >= cl && c   < ch) ? nv.x : C.x;
                nv.y = (rowin && c+1 >= cl && c+1 < ch) ? nv.y : C.y;
                nv.z = (rowin && c+2 >= cl && c+2 < ch) ? nv.z : C.z;
                nv.w = (rowin && c+3 >= cl && c+3 < ch) ? nv.w : C.w;
                *(float4*)&Rs[cur^1][r*JRW + c] = nv;
                Ct[k] = nv;
            }
        }
        __syncthreads();
        cur ^= 1;
    }

    #pragma unroll
    for (int k = 0; k < 4; ++k){
        int u = tid + k*NTH;
        if (u < JNU){
            int r = u / 18, c = (u % 18) << 2;
            if (r >= JH && r < JH+JIH && c >= JH && c < JH+JIW){
                int g = (ry0 + r)*WW + (cx0 + c);
                if (FINAL){
                    float4 d0 = *(const float4*)&disp0[g];
                    float4 o;
                    o.x = fmaxf(d0.x + Ct[k].x, 0.0f);
                    o.y = fmaxf(d0.y + Ct[k].y, 0.0f);
                    o.z = fmaxf(d0.z + Ct[k].z, 0.0f);
                    o.w = fmaxf(d0.w + Ct[k].w, 0.0f);
                    *(float4*)&out[g] = o;
                } else {
                    *(float4*)&Rout[g] = Ct[k];
                }
            }
        }
    }
}

extern "C" void kernel_launch(void* const* d_in, const int* in_sizes, int n_in,
                              void* d_out, int out_size, void* d_ws, size_t ws_size,
                              hipStream_t stream) {
    const float* P    = (const float*)d_in[0];
    const float* edge = (const float*)d_in[1];
    const float* occ  = (const float*)d_in[2];
    float* out = (float*)d_out;

    float*  conf   = (float*)d_ws;
    float*  disp0  = conf + HW;
    float*  nhat   = disp0 + HW;
    float*  Ra     = nhat + HW;
    float*  Rb     = Ra + HW;
    u32*    dhk    = (u32*)(Rb + HW);
    float4* w4raw  = (float4*)(dhk + HW);     // offset 24*HW B, 16B aligned
    float4* w4s    = w4raw + HW;
    u64*    list   = (u64*)(w4s + HW);
    SelState* st   = (SelState*)(list + HW);

    dim3 grid(NBLK), block(NTH);
    k_prob<<<grid, block, 0, stream>>>(P, edge, occ, conf, disp0, dhk, st);
    k_nms<<<grid, block, 0, stream>>>(conf, edge, occ, dhk, w4raw, list, st);
    k_sel<<<1, 1024, 0, stream>>>(list, st);

    dim3 jgrid(JGRID);
    // fused finalmaps: iter 1 staged + sweeps 2..11
    k_jacT<1,0><<<jgrid, block, 0, stream>>>(nullptr, Ra, w4raw, nullptr, w4s, nhat,
                                             conf, disp0, dhk, st, out, 10);
    // sweeps 12..21
    k_jacT<0,0><<<jgrid, block, 0, stream>>>(Ra, Rb, w4s, nhat, nullptr, nullptr,
                                             conf, disp0, dhk, st, out, 10);
    // sweeps 22..30 + clip
    k_jacT<0,1><<<jgrid, block, 0, stream>>>(Rb, nullptr, w4s, nhat, nullptr, nullptr,
                                             conf, disp0, dhk, st, out, 9);
}